// Round 6
// baseline (89.328 us; speedup 1.0000x reference)
//
#include <hip/hip_runtime.h>
#include <math.h>

// Problem constants (fixed by reference setup_inputs)
#define B_SZ 64
#define N_IN 1024
#define IDIM 64
#define NC   16
#define DC   32
#define TILE 256     // rows per LDS tile
#define NTILE 4      // tiles per batch
#define NTHR 1024    // 16 waves

// One block per batch: ALL reductions are intra-block (LDS + syncthreads).
// No workspace, no atomics, no cross-block sync, single launch.
__global__ __launch_bounds__(NTHR) void k_capsnet_fused(const float* __restrict__ x,
                                                        const float* __restrict__ W,
                                                        float* __restrict__ out) {
    const int b = blockIdx.x;
    const int tid = threadIdx.x, lane = tid & 63, wave = tid >> 6;

    // LDS (110 KB total -> 1 block/CU)
    __shared__ float xT[IDIM * TILE];               // 64 KB skewed: (n,i) -> xT[i*256+((n+i)&255)]
    __shared__ float __align__(16) wvT[IDIM * NC];  // 4 KB, [i][c]; accumulated across iters
    __shared__ float scrA[4096];                    // 16 KB: colSm / aSm / pSm (time-multiplexed)
    __shared__ float __align__(16) cwT[TILE * 20];  // 20 KB, [n][20] (pad 16->20 vs bank conflicts)
    __shared__ float redSm[NC * IDIM];              // 4 KB reduced xs / colsum
    __shared__ float __align__(16) vSm[NC * DC];    // 2 KB

    const float* xb = x + (size_t)b * (N_IN * IDIM);
    const float4* xb4 = reinterpret_cast<const float4*>(xb);

    // ---------------- pass 0: colsum (float4 streaming) ----------------
    {
        const int p = tid >> 4, i0 = (tid & 15) * 4;   // p = row residue 0..63
        float4 s4 = {0.f, 0.f, 0.f, 0.f};
#pragma unroll
        for (int k = 0; k < 16; k++) {
            const float4 v4 = xb4[(p + k * 64) * 16 + (tid & 15)];
            s4.x += v4.x; s4.y += v4.y; s4.z += v4.z; s4.w += v4.w;
        }
        scrA[p * 64 + i0 + 0] = s4.x;
        scrA[p * 64 + i0 + 1] = s4.y;
        scrA[p * 64 + i0 + 2] = s4.z;
        scrA[p * 64 + i0 + 3] = s4.w;
    }
    __syncthreads();
    if (tid < 64) {
        float r = 0.f;
#pragma unroll
        for (int p = 0; p < 64; p++) r += scrA[p * 64 + tid];
        redSm[tid] = r;                                 // colsum[i]
    }
    __syncthreads();

    // ---------------- capsule step: redSm -> v -> (wvT set/add | out) ----------------
    auto caps = [&](int mode) {   // 0: from colsum (scale 1/16), 1: wvT +=, 2: write out
        if (tid < 512) {
            const int c = tid >> 5, dd = tid & 31;
            const float* Wc = W + c * (IDIM * DC) + dd;
            float s = 0.f;
#pragma unroll 8
            for (int i = 0; i < IDIM; i++) {
                const float rv = (mode == 0) ? redSm[i] : redSm[c * 64 + i];
                s += rv * Wc[i * DC];
            }
            if (mode == 0) s *= 0.0625f;
            float n2 = s * s;
#pragma unroll
            for (int m = 16; m >= 1; m >>= 1) n2 += __shfl_xor(n2, m);  // 32-lane half
            const float g = (n2 / (1.f + n2)) / (sqrtf(n2) + 1e-8f);
            if (mode == 2) out[b * (NC * DC) + c * DC + dd] = g * s;
            else           vSm[c * DC + dd] = g * s;
        }
        __syncthreads();
        if (mode != 2) {
            const int i = lane, c = wave;               // 64 i x 16 c = 1024 threads
            const float4* Wr = reinterpret_cast<const float4*>(W + (size_t)(c * IDIM + i) * DC);
            const float4* vv = reinterpret_cast<const float4*>(vSm + c * DC);  // broadcast
            float acc = 0.f;
#pragma unroll
            for (int dq = 0; dq < 8; dq++) {
                const float4 wq = Wr[dq];
                const float4 vq = vv[dq];
                acc += wq.x * vq.x + wq.y * vq.y + wq.z * vq.z + wq.w * vq.w;
            }
            if (mode == 0) wvT[i * NC + c] = acc;
            else           wvT[i * NC + c] += acc;      // logits linear in wv: wv_eff = wv0+wv1
            __syncthreads();
        }
    };

    // ---------------- routing pass: logits -> softmax -> xs, tiled ----------------
    const int cg = wave >> 2, rg = wave & 3;   // cap-group (4 caps), row-quarter
    auto route_pass = [&]() {
        float acc4[4] = {0.f, 0.f, 0.f, 0.f};  // xs partial: caps cg*4..+3, lane = i
        float4 xr[4];
#pragma unroll
        for (int m = 0; m < 4; m++) xr[m] = xb4[tid + m * 1024];   // prefetch tile 0
        for (int t = 0; t < NTILE; t++) {
            __syncthreads();                   // xT free (prev tile's xs done)
#pragma unroll
            for (int m = 0; m < 4; m++) {      // skewed ds_write (<=2-way aliasing)
                const int f = tid + m * 1024, np = f >> 4, i0 = (f & 15) * 4;
                xT[(i0 + 0) * TILE + ((np + i0 + 0) & 255)] = xr[m].x;
                xT[(i0 + 1) * TILE + ((np + i0 + 1) & 255)] = xr[m].y;
                xT[(i0 + 2) * TILE + ((np + i0 + 2) & 255)] = xr[m].z;
                xT[(i0 + 3) * TILE + ((np + i0 + 3) & 255)] = xr[m].w;
            }
            __syncthreads();
            if (t + 1 < NTILE) {               // prefetch next tile (overlaps compute)
#pragma unroll
                for (int m = 0; m < 4; m++) xr[m] = xb4[(t + 1) * 4096 + tid + m * 1024];
            }
            // agreement: rows rg*64+lane, caps cg*4..+3 (wvT float4 broadcast)
            {
                const int row = rg * 64 + lane;
                float a4[4] = {0.f, 0.f, 0.f, 0.f};
#pragma unroll 8
                for (int i = 0; i < IDIM; i++) {
                    const float xv = xT[i * TILE + ((row + i) & 255)];
                    const float4 w4 = *reinterpret_cast<const float4*>(&wvT[i * NC + cg * 4]);
                    a4[0] += xv * w4.x; a4[1] += xv * w4.y;
                    a4[2] += xv * w4.z; a4[3] += xv * w4.w;
                }
#pragma unroll
                for (int cc = 0; cc < 4; cc++) scrA[(cg * 4 + cc) * TILE + row] = a4[cc];
            }
            __syncthreads();
            // softmax over 16 caps per row; 4 redundant groups, rotated regs (no dyn idx)
            {
                const int r = tid & 255, grp = tid >> 8;
                float av[NC];
#pragma unroll
                for (int k = 0; k < NC; k++) av[k] = scrA[((k + grp * 4) & 15) * TILE + r];
                float mx = av[0];
#pragma unroll
                for (int k = 1; k < NC; k++) mx = fmaxf(mx, av[k]);
                float ss = 0.f;
#pragma unroll
                for (int k = 0; k < NC; k++) { av[k] = __expf(av[k] - mx); ss += av[k]; }
                const float inv = 1.f / ss;
                float4 cw4;
                cw4.x = av[0] * inv; cw4.y = av[1] * inv;
                cw4.z = av[2] * inv; cw4.w = av[3] * inv;
                *reinterpret_cast<float4*>(&cwT[r * 20 + grp * 4]) = cw4;
            }
            __syncthreads();
            // xs accumulate: lane = i, rows rg*64..+63 (cwT float4 broadcast)
#pragma unroll 8
            for (int nl = 0; nl < 64; nl++) {
                const int np = rg * 64 + nl;
                const float xv = xT[lane * TILE + ((np + lane) & 255)];
                const float4 c4 = *reinterpret_cast<const float4*>(&cwT[np * 20 + cg * 4]);
                acc4[0] += xv * c4.x; acc4[1] += xv * c4.y;
                acc4[2] += xv * c4.z; acc4[3] += xv * c4.w;
            }
        }
        __syncthreads();                       // scrA (aSm) free -> pSm
#pragma unroll
        for (int cc = 0; cc < 4; cc++) scrA[rg * 1024 + (cg * 4 + cc) * 64 + lane] = acc4[cc];
        __syncthreads();
        redSm[tid & 1023] = scrA[tid] + scrA[1024 + tid] + scrA[2048 + tid] + scrA[3072 + tid];
        __syncthreads();
    };

    // iter 0 capsule (from colsum) -> wvT0
    caps(0);
    // iter 1: logits = x.wv0 -> softmax -> xs1 -> redSm
    route_pass();
    // v1; wvT = wv0 + wv1 (next logits = b1 + a1 = b2)
    caps(1);
    // iter 2: logits = x.(wv0+wv1) -> softmax -> xs2 -> redSm
    route_pass();
    // final squash -> out
    caps(2);
}

extern "C" void kernel_launch(void* const* d_in, const int* in_sizes, int n_in,
                              void* d_out, int out_size, void* d_ws, size_t ws_size,
                              hipStream_t stream) {
    const float* x = (const float*)d_in[0];    // [64,1024,64]
    const float* W = (const float*)d_in[1];    // [16,64,32]
    float* out = (float*)d_out;                // [64,16,32]
    (void)d_ws; (void)ws_size;

    k_capsnet_fused<<<B_SZ, NTHR, 0, stream>>>(x, W, out);
}

// Round 7
// 60.671 us; speedup vs baseline: 1.4723x; 1.4723x over previous
//
#include <hip/hip_runtime.h>
#include <math.h>

// Problem constants (fixed by reference setup_inputs)
#define B_SZ 64
#define N_IN 1024
#define IDIM 64
#define NC   16
#define DC   32
#define NQ   4      // blocks per batch
#define QR   256    // rows per block
#define NTHR 1024   // 16 waves

// Workspace (floats):
//  cnt : 64 ints   @ 0       per-batch arrival counters (reset each call by k_reset)
//  cs  : [256][64]   @ 64      colsum partials (agent-scope stores)
//  sp1 : [256][1024] @ 16448   xs partials iter 1
//  sp2 : [256][1024] @ 278592  xs partials iter 2
#define WS_CNT 0
#define WS_CS  64
#define WS_SP1 16448
#define WS_SP2 278592

__device__ __forceinline__ void st_agent(float* p, float v) {
    __hip_atomic_store(p, v, __ATOMIC_RELAXED, __HIP_MEMORY_SCOPE_AGENT);
}
__device__ __forceinline__ float ld_agent(const float* p) {
    return __hip_atomic_load(p, __ATOMIC_RELAXED, __HIP_MEMORY_SCOPE_AGENT);
}

__global__ __launch_bounds__(64) void k_reset(int* cnt) {
    __hip_atomic_store(&cnt[threadIdx.x], 0, __ATOMIC_RELAXED, __HIP_MEMORY_SCOPE_AGENT);
}

__global__ __launch_bounds__(NTHR, 1)
void k_fused(const float* __restrict__ x, const float* __restrict__ W,
             float* __restrict__ out, int* __restrict__ cnt,
             float* __restrict__ cs, float* __restrict__ sp1, float* __restrict__ sp2) {
    const int b = blockIdx.x >> 2, q = blockIdx.x & 3;
    const int tid = threadIdx.x, lane = tid & 63, wave = tid >> 6;
    const int row = tid & 255, grp = tid >> 8;          // agreement/softmax mapping
    const int rg = wave & 3;                            // row-quarter for xs

    // LDS ~106 KB -> exactly 1 block/CU; 256 blocks on 256 CUs (co-resident)
    __shared__ float xT[IDIM * QR];                 // 64 KB skewed: (n,i)->xT[i*256+((n+i)&255)]
    __shared__ float __align__(16) wvT[IDIM * NC];  // 4 KB [i][c], accumulated across iters
    __shared__ float scrA[4096];                    // 16 KB colSm/aSm/pSm (time-multiplexed)
    __shared__ float __align__(16) cwTT[NC * QR];   // 16 KB [c][n] (c-major: conflict-free)
    __shared__ float redSm[NC * IDIM];              // 4 KB
    __shared__ float __align__(16) vSm[NC * 36];    // padded stride 36 vs bank conflicts

    // ---- per-batch 4-block barrier (monotonic targets 4/8/12; cnt reset per call)
    auto barrier_batch = [&](int target) {
        __syncthreads();   // drains vmcnt: all agent-scope partial stores globally visible
        if (tid == 0) {
            __hip_atomic_fetch_add(&cnt[b], 1, __ATOMIC_RELEASE, __HIP_MEMORY_SCOPE_AGENT);
            while (__hip_atomic_load(&cnt[b], __ATOMIC_ACQUIRE,
                                     __HIP_MEMORY_SCOPE_AGENT) < target)
                __builtin_amdgcn_s_sleep(2);
        }
        __syncthreads();
    };

    // ---- stage this block's 256 rows into skewed-transposed LDS (read x ONCE)
    const float4* xb4 = reinterpret_cast<const float4*>(x + ((size_t)b * N_IN + q * QR) * IDIM);
#pragma unroll
    for (int m = 0; m < 4; m++) {
        const float4 v4 = xb4[tid + m * NTHR];
        const int np = (tid >> 4) + m * 64, i0 = (tid & 15) * 4;
        xT[(i0 + 0) * QR + ((np + i0 + 0) & 255)] = v4.x;
        xT[(i0 + 1) * QR + ((np + i0 + 1) & 255)] = v4.y;
        xT[(i0 + 2) * QR + ((np + i0 + 2) & 255)] = v4.z;
        xT[(i0 + 3) * QR + ((np + i0 + 3) & 255)] = v4.w;
    }
    __syncthreads();

    // ---- colsum partial from xT -> cs[b][q][i]
    {
        const int i = tid & 63, sg = tid >> 6;    // 16 groups x 16 rows
        float s = 0.f;
#pragma unroll
        for (int t = 0; t < 16; t++) {
            const int n = sg * 16 + t;
            s += xT[i * QR + ((n + i) & 255)];
        }
        scrA[sg * 64 + i] = s;
    }
    __syncthreads();
    if (tid < 64) {
        float r = 0.f;
#pragma unroll
        for (int s16 = 0; s16 < 16; s16++) r += scrA[s16 * 64 + tid];
        st_agent(&cs[(b * NQ + q) * 64 + tid], r);
    }
    barrier_batch(4);
    if (tid < 64) {
        float r = 0.f;
#pragma unroll
        for (int k = 0; k < NQ; k++) r += ld_agent(&cs[(b * NQ + k) * 64 + tid]);
        redSm[tid] = r;
    }
    __syncthreads();

    // ---- capsule step: redSm -> v -> (wvT set/add | out)
    auto caps = [&](int mode) {   // 0: colsum/16 -> wvT=, 1: wvT+=, 2: write out
        if (tid < 512) {
            const int c = tid >> 5, dd = tid & 31;
            const float* Wc = W + c * (IDIM * DC) + dd;
            float s = 0.f;
#pragma unroll 8
            for (int i = 0; i < IDIM; i++) {
                const float rv = (mode == 0) ? redSm[i] : redSm[c * 64 + i];
                s += rv * Wc[i * DC];
            }
            if (mode == 0) s *= 0.0625f;
            float n2 = s * s;
#pragma unroll
            for (int m = 16; m >= 1; m >>= 1) n2 += __shfl_xor(n2, m);  // 32-lane half
            const float g = (n2 / (1.f + n2)) / (sqrtf(n2) + 1e-8f);
            if (mode == 2) out[b * (NC * DC) + c * DC + dd] = g * s;
            else           vSm[c * 36 + dd] = g * s;
        }
        __syncthreads();
        if (mode != 2) {
            const int i = tid >> 4, c2 = tid & 15;   // lanes: consecutive c2 -> LDS-write free
            const float4* Wr = reinterpret_cast<const float4*>(W + (size_t)(c2 * IDIM + i) * DC);
            const float4* vv = reinterpret_cast<const float4*>(vSm + c2 * 36);
            float acc = 0.f;
#pragma unroll
            for (int dq = 0; dq < 8; dq++) {
                const float4 wq = Wr[dq];
                const float4 vq = vv[dq];            // <=2-way aliasing (pad 36)
                acc += wq.x * vq.x + wq.y * vq.y + wq.z * vq.z + wq.w * vq.w;
            }
            if (mode == 0) wvT[i * NC + c2] = acc;
            else           wvT[i * NC + c2] += acc;  // logit linearity: wv_eff = wv0+wv1
            __syncthreads();
        }
    };

    // ---- routing pass over this block's 256 rows -> xs partial sp[b][q][c][i]
    auto route = [&](float* sp) {
        // agreement: thread (row, grp) -> caps grp*4..+3
        float a4[4] = {0.f, 0.f, 0.f, 0.f};
#pragma unroll 8
        for (int i = 0; i < IDIM; i++) {
            const float xv = xT[i * QR + ((row + i) & 255)];
            const float4 w4 = *reinterpret_cast<const float4*>(&wvT[i * NC + grp * 4]);
            a4[0] += xv * w4.x; a4[1] += xv * w4.y; a4[2] += xv * w4.z; a4[3] += xv * w4.w;
        }
#pragma unroll
        for (int cc = 0; cc < 4; cc++) scrA[(grp * 4 + cc) * QR + row] = a4[cc];
        __syncthreads();
        // softmax over 16 caps per row (rotated indices: all compile-time)
        float av[NC];
#pragma unroll
        for (int k = 0; k < NC; k++) av[k] = scrA[((k + grp * 4) & 15) * QR + row];
        float mx = av[0];
#pragma unroll
        for (int k = 1; k < NC; k++) mx = fmaxf(mx, av[k]);
        float ss = 0.f;
#pragma unroll
        for (int k = 0; k < NC; k++) { av[k] = __expf(av[k] - mx); ss += av[k]; }
        const float inv = 1.f / ss;
#pragma unroll
        for (int cc = 0; cc < 4; cc++) cwTT[(grp * 4 + cc) * QR + row] = av[cc] * inv;
        __syncthreads();
        // xs: wave (grp, rg): caps grp*4..+3, rows rg*64..+63, lane = i
        float acc4[4] = {0.f, 0.f, 0.f, 0.f};
#pragma unroll
        for (int nl = 0; nl < 64; nl += 4) {
            const int base = rg * 64 + nl;
            const float4 c40 = *reinterpret_cast<const float4*>(&cwTT[(grp * 4 + 0) * QR + base]);
            const float4 c41 = *reinterpret_cast<const float4*>(&cwTT[(grp * 4 + 1) * QR + base]);
            const float4 c42 = *reinterpret_cast<const float4*>(&cwTT[(grp * 4 + 2) * QR + base]);
            const float4 c43 = *reinterpret_cast<const float4*>(&cwTT[(grp * 4 + 3) * QR + base]);
            const float xv0 = xT[lane * QR + ((base + 0 + lane) & 255)];
            const float xv1 = xT[lane * QR + ((base + 1 + lane) & 255)];
            const float xv2 = xT[lane * QR + ((base + 2 + lane) & 255)];
            const float xv3 = xT[lane * QR + ((base + 3 + lane) & 255)];
            acc4[0] += c40.x * xv0 + c40.y * xv1 + c40.z * xv2 + c40.w * xv3;
            acc4[1] += c41.x * xv0 + c41.y * xv1 + c41.z * xv2 + c41.w * xv3;
            acc4[2] += c42.x * xv0 + c42.y * xv1 + c42.z * xv2 + c42.w * xv3;
            acc4[3] += c43.x * xv0 + c43.y * xv1 + c43.z * xv2 + c43.w * xv3;
        }
        __syncthreads();                 // aSm reads long done; scrA -> pSm
#pragma unroll
        for (int cc = 0; cc < 4; cc++)
            scrA[rg * 1024 + (grp * 4 + cc) * 64 + lane] = acc4[cc];
        __syncthreads();
        const float val = scrA[tid] + scrA[1024 + tid] + scrA[2048 + tid] + scrA[3072 + tid];
        st_agent(&sp[(size_t)(b * NQ + q) * 1024 + tid], val);
    };

    // ---- iter 0 capsule
    caps(0);
    // ---- iter 1: route -> sp1; barrier; reduce; caps(1) (wvT += wv(v1))
    route(sp1);
    barrier_batch(8);
    {
        float r = 0.f;
#pragma unroll
        for (int k = 0; k < NQ; k++) r += ld_agent(&sp1[(size_t)(b * NQ + k) * 1024 + tid]);
        redSm[tid] = r;
    }
    __syncthreads();
    caps(1);
    // ---- iter 2: route -> sp2
    route(sp2);
    if (q != 0) {                         // producers done: signal and exit
        __syncthreads();
        if (tid == 0)
            __hip_atomic_fetch_add(&cnt[b], 1, __ATOMIC_RELEASE, __HIP_MEMORY_SCOPE_AGENT);
        return;
    }
    barrier_batch(12);
    {
        float r = 0.f;
#pragma unroll
        for (int k = 0; k < NQ; k++) r += ld_agent(&sp2[(size_t)(b * NQ + k) * 1024 + tid]);
        redSm[tid] = r;
    }
    __syncthreads();
    caps(2);                              // final squash -> out
}

extern "C" void kernel_launch(void* const* d_in, const int* in_sizes, int n_in,
                              void* d_out, int out_size, void* d_ws, size_t ws_size,
                              hipStream_t stream) {
    const float* x = (const float*)d_in[0];    // [64,1024,64]
    const float* W = (const float*)d_in[1];    // [16,64,32]
    float* out = (float*)d_out;                // [64,16,32]
    float* ws = (float*)d_ws;

    int*   cnt = (int*)(ws + WS_CNT);
    float* cs  = ws + WS_CS;
    float* sp1 = ws + WS_SP1;
    float* sp2 = ws + WS_SP2;

    k_reset<<<1, 64, 0, stream>>>(cnt);
    k_fused<<<B_SZ * NQ, NTHR, 0, stream>>>(x, W, out, cnt, cs, sp1, sp2);
}